// Round 13
// baseline (722.962 us; speedup 1.0000x reference)
//
#include <hip/hip_runtime.h>

#define BN_EPS 1e-5f

typedef unsigned short u16;
typedef __attribute__((ext_vector_type(8))) short bf16x8;
typedef __attribute__((ext_vector_type(4))) float f32x4;

__device__ __forceinline__ u16 f2bf(float x) {
  union { float f; unsigned int u; } v; v.f = x;
  unsigned int r = v.u + 0x7fffu + ((v.u >> 16) & 1u);
  return (u16)(r >> 16);
}
__device__ __forceinline__ float bf2f(u16 h) {
  union { unsigned int u; float f; } v; v.u = ((unsigned int)h) << 16;
  return v.f;
}

__device__ __forceinline__ float wave_reduce_sum(float v) {
#pragma unroll
  for (int off = 1; off < 64; off <<= 1) v += __shfl_xor(v, off, 64);
  return v;
}

// async global->LDS, 16B per lane. LDS dest = wave-uniform base + lane*16.
__device__ __forceinline__ void gload_lds16(const void* g, void* l) {
  __builtin_amdgcn_global_load_lds(
      (const __attribute__((address_space(1))) void*)g,
      (__attribute__((address_space(3))) void*)l, 16, 0, 0);
}

// ---------------------------------------------------------------------------
// embed_prep: blocks [0,512): 32 rows each -> fm_first (bf16) + partial[n].
// blocks [512,584): W1 -> W1h bf16 padded to 512 rows; block 512 also zeroes
//   the 4x512 atomic stat accumulators. (b1/biases cancel through train-BN.)
// ---------------------------------------------------------------------------
__global__ __launch_bounds__(256) void embed_prep(
    const float* __restrict__ Xi_dense, const float* __restrict__ Xv,
    const float* __restrict__ Wd, const float* __restrict__ bd,
    const float* __restrict__ tables, const int* __restrict__ Xi_cat,
    const float* __restrict__ bias_vec, const float* __restrict__ W1,
    u16* __restrict__ fm_first, float* __restrict__ partial,
    u16* __restrict__ W1h, float* __restrict__ statz) {
  const int t = threadIdx.x;
  if (blockIdx.x >= 512) {  // W1 conversion region (+ stat zeroing)
    const int bb = blockIdx.x - 512;
    if (bb == 0) {
#pragma unroll
      for (int i = 0; i < 8; ++i) statz[i * 256 + t] = 0.f;  // 2048 floats
    }
    const int base = bb * 4096;
#pragma unroll
    for (int e = 0; e < 16; ++e) {
      const int idx = base + e * 256 + t;
      const int r = idx / 576;
      const int j = idx - r * 576;
      W1h[idx] = (r < 400) ? f2bf(W1[r * 576 + j]) : (u16)0;
    }
    return;
  }

  __shared__ float Xvs[32 * 37];
  __shared__ float Xds[32 * 27];
  __shared__ int Cis[32 * 11];
  __shared__ float Wds[416], Bds[416];
  const int n0 = blockIdx.x * 32;

  for (int i = t; i < 1152; i += 256) {
    const int r = i / 36;
    Xvs[r * 37 + (i - r * 36)] = Xv[n0 * 36 + i];
  }
  for (int i = t; i < 832; i += 256) {
    const int r = i / 26;
    Xds[r * 27 + (i - r * 26)] = Xi_dense[n0 * 26 + i];
  }
  for (int i = t; i < 320; i += 256) {
    const int r = i / 10;
    Cis[r * 11 + (i - r * 10)] = Xi_cat[n0 * 10 + i];
  }
  for (int i = t; i < 416; i += 256) {
    Wds[i] = Wd[i];
    Bds[i] = bd[i];
  }
  __syncthreads();

  const int r = t >> 3, q = t & 7;
  const int n = n0 + r;
  const int fbase = q >> 1, eh = (q & 1) * 8;
  float s8[8] = {}, q8[8] = {};
  float sum_all = 0.f;
  u16* frow = fm_first + (size_t)n * 576;

#pragma unroll
  for (int j = 0; j < 9; ++j) {
    const int f = fbase + 4 * j;
    const float xvv = Xvs[r * 37 + f];
    float val[8];
    if (f < 26) {  // dense field: x*W + b, then scale by xv
      const float xd = Xds[r * 27 + f];
      const float4 w0 = *(const float4*)&Wds[f * 16 + eh];
      const float4 w1 = *(const float4*)&Wds[f * 16 + eh + 4];
      const float4 b0 = *(const float4*)&Bds[f * 16 + eh];
      const float4 b1v = *(const float4*)&Bds[f * 16 + eh + 4];
      val[0] = fmaf(xd, w0.x, b0.x) * xvv;
      val[1] = fmaf(xd, w0.y, b0.y) * xvv;
      val[2] = fmaf(xd, w0.z, b0.z) * xvv;
      val[3] = fmaf(xd, w0.w, b0.w) * xvv;
      val[4] = fmaf(xd, w1.x, b1v.x) * xvv;
      val[5] = fmaf(xd, w1.y, b1v.y) * xvv;
      val[6] = fmaf(xd, w1.z, b1v.z) * xvv;
      val[7] = fmaf(xd, w1.w, b1v.w) * xvv;
    } else {  // categorical gather
      const int fc = f - 26;
      const int row = Cis[r * 11 + fc];
      const float* tp =
          tables + ((size_t)fc * 200000 + (size_t)row) * 16 + eh;
      const float4 v0 = *(const float4*)tp;
      const float4 v1 = *(const float4*)(tp + 4);
      val[0] = v0.x * xvv;
      val[1] = v0.y * xvv;
      val[2] = v0.z * xvv;
      val[3] = v0.w * xvv;
      val[4] = v1.x * xvv;
      val[5] = v1.y * xvv;
      val[6] = v1.z * xvv;
      val[7] = v1.w * xvv;
    }
    bf16x8 o;
#pragma unroll
    for (int jj = 0; jj < 8; ++jj) {
      s8[jj] += val[jj];
      q8[jj] += val[jj] * val[jj];
      sum_all += val[jj];
      o[jj] = (short)f2bf(val[jj]);
    }
    *(bf16x8*)&frow[f * 16 + eh] = o;
  }

  // combine fields across the 4 fbase classes (xor 2,4), per e-column
  float fm2h = 0.f;
#pragma unroll
  for (int jj = 0; jj < 8; ++jj) {
    float se = s8[jj] + __shfl_xor(s8[jj], 2, 64);
    se += __shfl_xor(se, 4, 64);
    float qe = q8[jj] + __shfl_xor(q8[jj], 2, 64);
    qe += __shfl_xor(qe, 4, 64);
    fm2h += se * se - qe;
  }
  const float fm2 = 0.5f * (fm2h + __shfl_xor(fm2h, 1, 64));  // both e-halves
  float srow = sum_all + __shfl_xor(sum_all, 1, 64);
  srow += __shfl_xor(srow, 2, 64);
  srow += __shfl_xor(srow, 4, 64);
  if (q == 0) partial[n] = srow + fm2 + bias_vec[n];
}

// ---------------------------------------------------------------------------
// bf16 MFMA GEMM body (r12 config: dbuf, counted vmcnt(3), T2 XOR-swizzle).
// PROBE: do_stats gates the atomicAdd epilogue to rep 0 (exactly-once).
// ---------------------------------------------------------------------------
template <int NFR>
__device__ __forceinline__ void gemm_body(
    const u16* __restrict__ A, int lda, const u16* __restrict__ W, int ldw,
    u16* __restrict__ Y, int ldc, int Ncap, float* __restrict__ aS,
    float* __restrict__ aQ, int K, int bx, int by, u16 (*As)[64 * 32],
    u16 (*Bs)[128 * 32], float (&rS)[2][4][2][16],
    float (&rQ)[2][4][2][16], bool do_stats) {
  const int t = threadIdx.x;
  const int bm = bx * 64;
  const int bn = by * 128;
  const int wid = t >> 6, lane = t & 63;
  const int wr = wid >> 1, wc = wid & 1;
  const int lr = lane & 15;
  const int sr = lane >> 2;       // staging row within 16-row chunk
  const int ssw = (((lane & 3) ^ ((sr >> 1) & 3))) * 8;   // staging slot swz
  const int lkS = (((lane >> 4) ^ ((lr >> 1) & 3))) * 8;  // frag-read slot swz
  const bool active = (NFR == 4) || (wc == 0);

  f32x4 acc[2][NFR] = {};

  auto STAGE = [&](int buf, int kt) {
    gload_lds16(&A[(size_t)(bm + wid * 16 + sr) * lda + kt + ssw],
                &As[buf][wid * 512]);
#pragma unroll
    for (int i = 0; i < 2; ++i) {
      const int c = (NFR == 4) ? (wid * 2 + i) : i;
      gload_lds16(&W[(size_t)(bn + c * 16 + sr) * ldw + kt + ssw],
                  &Bs[buf][c * 512]);
    }
  };

  auto COMPUTE = [&](int buf) {
    if (active) {
      bf16x8 af[2], bfv[NFR];
#pragma unroll
      for (int mf = 0; mf < 2; ++mf)
        af[mf] = *(const bf16x8*)&As[buf][(wr * 32 + mf * 16 + lr) * 32 + lkS];
#pragma unroll
      for (int nf = 0; nf < NFR; ++nf)
        bfv[nf] =
            *(const bf16x8*)&Bs[buf][(wc * 64 + nf * 16 + lr) * 32 + lkS];
      __builtin_amdgcn_s_setprio(1);
#pragma unroll
      for (int mf = 0; mf < 2; ++mf)
#pragma unroll
        for (int nf = 0; nf < NFR; ++nf)
          acc[mf][nf] = __builtin_amdgcn_mfma_f32_16x16x32_bf16(
              af[mf], bfv[nf], acc[mf][nf], 0, 0, 0);
      __builtin_amdgcn_s_setprio(0);
    }
  };

  STAGE(0, 0);
  int cur = 0;
  for (int kt = 32; kt < K; kt += 32) {
    STAGE(cur ^ 1, kt);
    asm volatile("s_waitcnt vmcnt(3)" ::: "memory");
    __builtin_amdgcn_s_barrier();
    COMPUTE(cur);
    __builtin_amdgcn_s_barrier();
    cur ^= 1;
  }
  asm volatile("s_waitcnt vmcnt(0)" ::: "memory");
  __builtin_amdgcn_s_barrier();
  COMPUTE(cur);  // last tile

  // epilogue: bf16 store, per-block column stats (stats only when do_stats)
  const int l4 = (lane >> 4) * 4;
  __syncthreads();
  if (active) {
#pragma unroll
    for (int nf = 0; nf < NFR; ++nf) {
      const int col = bn + wc * 64 + nf * 16 + lr;
      float s = 0.f, q = 0.f;
#pragma unroll
      for (int mf = 0; mf < 2; ++mf) {
#pragma unroll
        for (int r = 0; r < 4; ++r) {
          const int row = bm + wr * 32 + mf * 16 + l4 + r;
          const float v = acc[mf][nf][r];
          s += v;
          q += v * v;
          if (col < Ncap) Y[(size_t)row * ldc + col] = f2bf(v);
        }
      }
      s += __shfl_xor(s, 16, 64);
      s += __shfl_xor(s, 32, 64);
      q += __shfl_xor(q, 16, 64);
      q += __shfl_xor(q, 32, 64);
      if (lane < 16) {
        rS[wc][nf][wr][lr] = s;
        rQ[wc][nf][wr][lr] = q;
      }
    }
  }
  __syncthreads();
  if (do_stats && t < (NFR == 4 ? 128 : 32)) {  // t == wc*64 + nf*16 + c
    const int wcc = t >> 6, nff = (t >> 4) & 3, c = t & 15;
    atomicAdd(&aS[bn + t], rS[wcc][nff][0][c] + rS[wcc][nff][1][c]);
    atomicAdd(&aQ[bn + t], rQ[wcc][nff][0][c] + rQ[wcc][nff][1][c]);
  }
}

// 1-D grid, y-inner ordering + XCD-chunked swizzle (grid %8 == 0).
// PROBE: reps-amplified; stats epilogue on rep 0 only; Y stores idempotent.
__global__ __launch_bounds__(256) void gemm_bf16(
    const u16* __restrict__ A, int lda,
    const u16* __restrict__ W, int ldw,
    u16* __restrict__ Y, int ldc, int Ncap,
    float* __restrict__ aS, float* __restrict__ aQ, int K, int reps) {
  __shared__ u16 As[2][64 * 32];
  __shared__ u16 Bs[2][128 * 32];
  __shared__ float rS[2][4][2][16];
  __shared__ float rQ[2][4][2][16];
  const int bid = blockIdx.x;
  const int l = (bid & 7) * (gridDim.x >> 3) + (bid >> 3);
  const int bx = l >> 2, by = l & 3;
  for (int rep = 0; rep < reps; ++rep) {
    if (by < 3)
      gemm_body<4>(A, lda, W, ldw, Y, ldc, Ncap, aS, aQ, K, bx, by, As, Bs,
                   rS, rQ, rep == 0);
    else
      gemm_body<2>(A, lda, W, ldw, Y, ldc, Ncap, aS, aQ, K, bx, by, As, Bs,
                   rS, rQ, rep == 0);
    __syncthreads();
  }
}

// ---------------------------------------------------------------------------
// prep2: W2p[i][j] = bf16(W2[i][j] * a1[j]), a1 inline from atomic stats.
// ---------------------------------------------------------------------------
__global__ __launch_bounds__(256) void prep2(
    const float* __restrict__ aS1, const float* __restrict__ aQ1,
    const float* __restrict__ g1, const float* __restrict__ W2,
    u16* __restrict__ W2p) {
  const int c = blockIdx.x * 256 + threadIdx.x;  // 512*104 chunks
  const int row = c / 104;
  const int jc = (c - row * 104) * 4;
  ushort4 o = {0, 0, 0, 0};
  if (row < 400 && jc < 400) {
    const float4 S = *(const float4*)&aS1[jc];
    const float4 Q = *(const float4*)&aQ1[jc];
    const float4 G = *(const float4*)&g1[jc];
    const float4 w = *(const float4*)&W2[(size_t)row * 400 + jc];
    const float inv = 1.f / 16384.f;
    float mu, var, a;
    mu = S.x * inv; var = Q.x * inv - mu * mu;
    a = G.x * rsqrtf(var + BN_EPS); o.x = f2bf(w.x * a);
    mu = S.y * inv; var = Q.y * inv - mu * mu;
    a = G.y * rsqrtf(var + BN_EPS); o.y = f2bf(w.y * a);
    mu = S.z * inv; var = Q.z * inv - mu * mu;
    a = G.z * rsqrtf(var + BN_EPS); o.z = f2bf(w.z * a);
    mu = S.w * inv; var = Q.w * inv - mu * mu;
    a = G.w * rsqrtf(var + BN_EPS); o.w = f2bf(w.w * a);
  }
  *(ushort4*)&W2p[(size_t)row * 416 + jc] = o;
}

// ---------------------------------------------------------------------------
// final: BN2 affine inline per lane (8 cols) + row dot.
// ---------------------------------------------------------------------------
__device__ __forceinline__ void bn_affine4(const float* aS, const float* aQ,
                                           const float* g, const float* be,
                                           int j, float4& aa, float4& cc) {
  const float4 S = *(const float4*)&aS[j];
  const float4 Q = *(const float4*)&aQ[j];
  const float4 G = *(const float4*)&g[j];
  const float4 E = *(const float4*)&be[j];
  const float inv = 1.f / 16384.f;
  float mu, var;
  mu = S.x * inv; var = Q.x * inv - mu * mu;
  aa.x = G.x * rsqrtf(var + BN_EPS); cc.x = E.x - mu * aa.x;
  mu = S.y * inv; var = Q.y * inv - mu * mu;
  aa.y = G.y * rsqrtf(var + BN_EPS); cc.y = E.y - mu * aa.y;
  mu = S.z * inv; var = Q.z * inv - mu * mu;
  aa.z = G.z * rsqrtf(var + BN_EPS); cc.z = E.z - mu * aa.z;
  mu = S.w * inv; var = Q.w * inv - mu * mu;
  aa.w = G.w * rsqrtf(var + BN_EPS); cc.w = E.w - mu * aa.w;
}

__global__ __launch_bounds__(256) void final_kernel(
    const u16* __restrict__ Y2, const float* __restrict__ aS2,
    const float* __restrict__ aQ2, const float* __restrict__ g2,
    const float* __restrict__ be2, const float* __restrict__ partial,
    float* __restrict__ out) {
  const int t = threadIdx.x;
  const int lane = t & 63;
  const int wid = t >> 6;
  const int j0 = lane * 8;
  float ar[8], cr[8];
  if (j0 < 400) {
    float4 aa0, cc0, aa1, cc1;
    bn_affine4(aS2, aQ2, g2, be2, j0, aa0, cc0);
    bn_affine4(aS2, aQ2, g2, be2, j0 + 4, aa1, cc1);
    ar[0] = aa0.x; ar[1] = aa0.y; ar[2] = aa0.z; ar[3] = aa0.w;
    ar[4] = aa1.x; ar[5] = aa1.y; ar[6] = aa1.z; ar[7] = aa1.w;
    cr[0] = cc0.x; cr[1] = cc0.y; cr[2] = cc0.z; cr[3] = cc0.w;
    cr[4] = cc1.x; cr[5] = cc1.y; cr[6] = cc1.z; cr[7] = cc1.w;
  } else {
#pragma unroll
    for (int k = 0; k < 8; ++k) { ar[k] = 0.f; cr[k] = 0.f; }
  }
#pragma unroll
  for (int r = 0; r < 4; ++r) {
    const int n = blockIdx.x * 16 + wid * 4 + r;
    float acc = 0.f;
    if (j0 < 400) {
      const bf16x8 y = *(const bf16x8*)&Y2[(size_t)n * 400 + j0];
#pragma unroll
      for (int k = 0; k < 8; ++k)
        acc += fmaf(ar[k], bf2f((u16)y[k]), cr[k]);
    }
    acc = wave_reduce_sum(acc);
    if (lane == 0) out[n] = partial[n] + acc;
  }
}

extern "C" void kernel_launch(void* const* d_in, const int* in_sizes, int n_in,
                              void* d_out, int out_size, void* d_ws,
                              size_t ws_size, hipStream_t stream) {
  const float* Xi_dense = (const float*)d_in[0];
  const float* Xv = (const float*)d_in[1];
  const float* Wd = (const float*)d_in[2];
  const float* bd = (const float*)d_in[3];
  const float* tables = (const float*)d_in[4];
  const float* W1 = (const float*)d_in[5];
  const float* g1 = (const float*)d_in[7];
  const float* W2 = (const float*)d_in[9];
  const float* g2 = (const float*)d_in[11];
  const float* be2 = (const float*)d_in[12];
  const float* bias_vec = (const float*)d_in[13];
  const int* Xi_cat = (const int*)d_in[14];

  constexpr int N = 16384;
  constexpr int DIN = 576;
  constexpr int H = 400;
  constexpr int KP = 416;   // H padded to K-mult-of-32 for gemm2
  constexpr int WPAD = 512; // weight rows padded for unpredicated staging
  constexpr int NXB = 256;  // gemm x-blocks (N/64)

  u16* fm_first = (u16*)d_ws;                        // N*576
  u16* Y1h = fm_first + (size_t)N * DIN;             // N*416
  u16* Y2h = Y1h + (size_t)N * KP;                   // N*400
  u16* W1h = Y2h + (size_t)N * H;                    // 512*576
  u16* W2p = W1h + (size_t)WPAD * DIN;               // 512*416
  float* fptr = (float*)(W2p + (size_t)WPAD * KP);
  float* partial = fptr;                             // N
  float* aS1 = partial + N;                          // 512 (stats; 2048
  float* aQ1 = aS1 + WPAD;                           //  floats zeroed by
  float* aS2 = aQ1 + WPAD;                           //  embed block 512)
  float* aQ2 = aS2 + WPAD;

  // PROBE ROUND: gemm1 x16, gemm2 x24 amplified (stats on rep 0 only) so
  // the GEMM dispatches surface in top-5 with full counters.
  embed_prep<<<512 + 72, 256, 0, stream>>>(Xi_dense, Xv, Wd, bd, tables,
                                           Xi_cat, bias_vec, W1, fm_first,
                                           partial, W1h, aS1);

  gemm_bf16<<<NXB * 4, 256, 0, stream>>>(fm_first, DIN, W1h, DIN,
                                         Y1h, KP, KP, aS1, aQ1, DIN, 16);

  prep2<<<208, 256, 0, stream>>>(aS1, aQ1, g1, W2, W2p);

  gemm_bf16<<<NXB * 4, 256, 0, stream>>>(Y1h, KP, W2p, KP,
                                         Y2h, H, H, aS2, aQ2, KP, 24);

  final_kernel<<<N / 16, 256, 0, stream>>>(Y2h, aS2, aQ2, g2, be2, partial,
                                           (float*)d_out);
}

// Round 14
// 57.828 us; speedup vs baseline: 12.5019x; 12.5019x over previous
//
#include <hip/hip_runtime.h>

#define BN_EPS 1e-5f

typedef unsigned short u16;
typedef __attribute__((ext_vector_type(8))) short bf16x8;
typedef __attribute__((ext_vector_type(4))) float f32x4;

__device__ __forceinline__ u16 f2bf(float x) {
  union { float f; unsigned int u; } v; v.f = x;
  unsigned int r = v.u + 0x7fffu + ((v.u >> 16) & 1u);
  return (u16)(r >> 16);
}
__device__ __forceinline__ float bf2f(u16 h) {
  union { unsigned int u; float f; } v; v.u = ((unsigned int)h) << 16;
  return v.f;
}

__device__ __forceinline__ float wave_reduce_sum(float v) {
#pragma unroll
  for (int off = 1; off < 64; off <<= 1) v += __shfl_xor(v, off, 64);
  return v;
}

// async global->LDS, 16B per lane. LDS dest = wave-uniform base + lane*16.
__device__ __forceinline__ void gload_lds16(const void* g, void* l) {
  __builtin_amdgcn_global_load_lds(
      (const __attribute__((address_space(1))) void*)g,
      (__attribute__((address_space(3))) void*)l, 16, 0, 0);
}

// ---------------------------------------------------------------------------
// embed_prep: blocks [0,512): 32 rows each -> fm_first (bf16) + partial[n].
// blocks [512,584): W1 -> W1h bf16 padded to 512 rows; block 512 also zeroes
//   the 4x512 atomic stat accumulators. (b1/biases cancel through train-BN.)
// ---------------------------------------------------------------------------
__global__ __launch_bounds__(256) void embed_prep(
    const float* __restrict__ Xi_dense, const float* __restrict__ Xv,
    const float* __restrict__ Wd, const float* __restrict__ bd,
    const float* __restrict__ tables, const int* __restrict__ Xi_cat,
    const float* __restrict__ bias_vec, const float* __restrict__ W1,
    u16* __restrict__ fm_first, float* __restrict__ partial,
    u16* __restrict__ W1h, float* __restrict__ statz) {
  const int t = threadIdx.x;
  if (blockIdx.x >= 512) {  // W1 conversion region (+ stat zeroing)
    const int bb = blockIdx.x - 512;
    if (bb == 0) {
#pragma unroll
      for (int i = 0; i < 8; ++i) statz[i * 256 + t] = 0.f;  // 2048 floats
    }
    const int base = bb * 4096;
#pragma unroll
    for (int e = 0; e < 16; ++e) {
      const int idx = base + e * 256 + t;
      const int r = idx / 576;
      const int j = idx - r * 576;
      W1h[idx] = (r < 400) ? f2bf(W1[r * 576 + j]) : (u16)0;
    }
    return;
  }

  __shared__ float Xvs[32 * 37];
  __shared__ float Xds[32 * 27];
  __shared__ int Cis[32 * 11];
  __shared__ float Wds[416], Bds[416];
  const int n0 = blockIdx.x * 32;

  for (int i = t; i < 1152; i += 256) {
    const int r = i / 36;
    Xvs[r * 37 + (i - r * 36)] = Xv[n0 * 36 + i];
  }
  for (int i = t; i < 832; i += 256) {
    const int r = i / 26;
    Xds[r * 27 + (i - r * 26)] = Xi_dense[n0 * 26 + i];
  }
  for (int i = t; i < 320; i += 256) {
    const int r = i / 10;
    Cis[r * 11 + (i - r * 10)] = Xi_cat[n0 * 10 + i];
  }
  for (int i = t; i < 416; i += 256) {
    Wds[i] = Wd[i];
    Bds[i] = bd[i];
  }
  __syncthreads();

  const int r = t >> 3, q = t & 7;
  const int n = n0 + r;
  const int fbase = q >> 1, eh = (q & 1) * 8;
  float s8[8] = {}, q8[8] = {};
  float sum_all = 0.f;
  u16* frow = fm_first + (size_t)n * 576;

#pragma unroll
  for (int j = 0; j < 9; ++j) {
    const int f = fbase + 4 * j;
    const float xvv = Xvs[r * 37 + f];
    float val[8];
    if (f < 26) {  // dense field: x*W + b, then scale by xv
      const float xd = Xds[r * 27 + f];
      const float4 w0 = *(const float4*)&Wds[f * 16 + eh];
      const float4 w1 = *(const float4*)&Wds[f * 16 + eh + 4];
      const float4 b0 = *(const float4*)&Bds[f * 16 + eh];
      const float4 b1v = *(const float4*)&Bds[f * 16 + eh + 4];
      val[0] = fmaf(xd, w0.x, b0.x) * xvv;
      val[1] = fmaf(xd, w0.y, b0.y) * xvv;
      val[2] = fmaf(xd, w0.z, b0.z) * xvv;
      val[3] = fmaf(xd, w0.w, b0.w) * xvv;
      val[4] = fmaf(xd, w1.x, b1v.x) * xvv;
      val[5] = fmaf(xd, w1.y, b1v.y) * xvv;
      val[6] = fmaf(xd, w1.z, b1v.z) * xvv;
      val[7] = fmaf(xd, w1.w, b1v.w) * xvv;
    } else {  // categorical gather
      const int fc = f - 26;
      const int row = Cis[r * 11 + fc];
      const float* tp =
          tables + ((size_t)fc * 200000 + (size_t)row) * 16 + eh;
      const float4 v0 = *(const float4*)tp;
      const float4 v1 = *(const float4*)(tp + 4);
      val[0] = v0.x * xvv;
      val[1] = v0.y * xvv;
      val[2] = v0.z * xvv;
      val[3] = v0.w * xvv;
      val[4] = v1.x * xvv;
      val[5] = v1.y * xvv;
      val[6] = v1.z * xvv;
      val[7] = v1.w * xvv;
    }
    bf16x8 o;
#pragma unroll
    for (int jj = 0; jj < 8; ++jj) {
      s8[jj] += val[jj];
      q8[jj] += val[jj] * val[jj];
      sum_all += val[jj];
      o[jj] = (short)f2bf(val[jj]);
    }
    *(bf16x8*)&frow[f * 16 + eh] = o;
  }

  // combine fields across the 4 fbase classes (xor 2,4), per e-column
  float fm2h = 0.f;
#pragma unroll
  for (int jj = 0; jj < 8; ++jj) {
    float se = s8[jj] + __shfl_xor(s8[jj], 2, 64);
    se += __shfl_xor(se, 4, 64);
    float qe = q8[jj] + __shfl_xor(q8[jj], 2, 64);
    qe += __shfl_xor(qe, 4, 64);
    fm2h += se * se - qe;
  }
  const float fm2 = 0.5f * (fm2h + __shfl_xor(fm2h, 1, 64));  // both e-halves
  float srow = sum_all + __shfl_xor(sum_all, 1, 64);
  srow += __shfl_xor(srow, 2, 64);
  srow += __shfl_xor(srow, 4, 64);
  if (q == 0) partial[n] = srow + fm2 + bias_vec[n];
}

// ---------------------------------------------------------------------------
// bf16 MFMA GEMM — LDS-bandwidth-optimized (r13 probe: MfmaUtil 14%, all
// pipes idle -> LDS-BW bound; 678 MB LDS traffic at BM=64).
//   BM=128 BN=128 BK=64, 256 thr = 4 waves (2x2), wave = 64x64 out (4x4
//   frags, 32 MFMA/step) -> 512 B LDS-read/MFMA (was 768), B-restaging
//   halved; 9/7 K-steps (was 18/13). Double-buffer + counted vmcnt(8).
// LDS rows are 128B = 8 slots of 16B; slot swizzle (both-sides, rule 21):
//   phys_slot = logical_slot ^ (row & 7)
// applied to the global source during gload_lds (linear LDS dest) and to
// the ds_read address -> all 32 banks covered per frag read.
// Weight rows are zero-padded to 512, so the by=3 tail computes a full
// 128-col tile (zeros beyond 448) — uniform code path, stores col<Ncap.
// Stats: per-block column S/Q atomicAdd into aS/aQ[col] (512-wide).
// ---------------------------------------------------------------------------
__global__ __launch_bounds__(256) void gemm_bf16(
    const u16* __restrict__ A, int lda,
    const u16* __restrict__ W, int ldw,
    u16* __restrict__ Y, int ldc, int Ncap,
    float* __restrict__ aS, float* __restrict__ aQ, int K) {
  __shared__ u16 As[2][128 * 64];
  __shared__ u16 Bs[2][128 * 64];
  __shared__ float rS[2][4][2][16];
  __shared__ float rQ[2][4][2][16];

  const int t = threadIdx.x;
  const int bid = blockIdx.x;
  const int l = (bid & 7) * (gridDim.x >> 3) + (bid >> 3);  // XCD chunk swz
  const int bx = l >> 2, by = l & 3;                        // y-inner
  const int bm = bx * 128, bn = by * 128;
  const int wid = t >> 6, lane = t & 63;
  const int wr = wid >> 1, wc = wid & 1;
  const int lr = lane & 15, hi = lane >> 4;
  const int sr = lane >> 3;                 // staging row within 8-row chunk
  const int sl = ((lane & 7) ^ sr) * 8;     // pre-swizzled source slot (elems)

  f32x4 acc[4][4] = {};

  // 8 gload_lds per wave per call (uniform): waves 0,1 stage A; 2,3 stage B.
  auto STAGE = [&](int buf, int kt) {
#pragma unroll
    for (int i = 0; i < 8; ++i) {
      const int c = (wid & 1) * 8 + i;  // chunk = 8 rows x 128 B = 1 KB
      if (wid < 2)
        gload_lds16(&A[(size_t)(bm + c * 8 + sr) * lda + kt + sl],
                    &As[buf][c * 512]);
      else
        gload_lds16(&W[(size_t)(bn + c * 8 + sr) * ldw + kt + sl],
                    &Bs[buf][c * 512]);
    }
  };

  auto COMPUTE = [&](int buf) {
#pragma unroll
    for (int ks = 0; ks < 2; ++ks) {
      const int ps = ((ks * 4 + hi) ^ (lr & 7)) * 8;  // swizzled slot (elems)
      bf16x8 af[4], bfv[4];
#pragma unroll
      for (int mf = 0; mf < 4; ++mf)
        af[mf] = *(const bf16x8*)&As[buf][(wr * 64 + mf * 16 + lr) * 64 + ps];
#pragma unroll
      for (int nf = 0; nf < 4; ++nf)
        bfv[nf] =
            *(const bf16x8*)&Bs[buf][(wc * 64 + nf * 16 + lr) * 64 + ps];
      __builtin_amdgcn_s_setprio(1);
#pragma unroll
      for (int mf = 0; mf < 4; ++mf)
#pragma unroll
        for (int nf = 0; nf < 4; ++nf)
          acc[mf][nf] = __builtin_amdgcn_mfma_f32_16x16x32_bf16(
              af[mf], bfv[nf], acc[mf][nf], 0, 0, 0);
      __builtin_amdgcn_s_setprio(0);
    }
  };

  STAGE(0, 0);
  int cur = 0;
  for (int kt = 64; kt < K; kt += 64) {
    STAGE(cur ^ 1, kt);  // next tile's 8 loads in flight
    asm volatile("s_waitcnt vmcnt(8)" ::: "memory");  // cur's 8 retired
    __builtin_amdgcn_s_barrier();
    COMPUTE(cur);
    __builtin_amdgcn_s_barrier();  // all reads done before re-stage
    cur ^= 1;
  }
  asm volatile("s_waitcnt vmcnt(0)" ::: "memory");
  __builtin_amdgcn_s_barrier();
  COMPUTE(cur);  // last tile

  // epilogue: bf16 store (col<Ncap), per-block column stats
  const int l4 = hi * 4;
  __syncthreads();
#pragma unroll
  for (int nf = 0; nf < 4; ++nf) {
    const int col = bn + wc * 64 + nf * 16 + lr;
    float s = 0.f, q = 0.f;
#pragma unroll
    for (int mf = 0; mf < 4; ++mf) {
#pragma unroll
      for (int r = 0; r < 4; ++r) {
        const int row = bm + wr * 64 + mf * 16 + l4 + r;
        const float v = acc[mf][nf][r];
        s += v;
        q += v * v;
        if (col < Ncap) Y[(size_t)row * ldc + col] = f2bf(v);
      }
    }
    s += __shfl_xor(s, 16, 64);
    s += __shfl_xor(s, 32, 64);
    q += __shfl_xor(q, 16, 64);
    q += __shfl_xor(q, 32, 64);
    if (lane < 16) {
      rS[wc][nf][wr][lr] = s;
      rQ[wc][nf][wr][lr] = q;
    }
  }
  __syncthreads();
  if (t < 128) {  // t == wc*64 + nf*16 + c
    const int wcc = t >> 6, nff = (t >> 4) & 3, c = t & 15;
    atomicAdd(&aS[bn + t], rS[wcc][nff][0][c] + rS[wcc][nff][1][c]);
    atomicAdd(&aQ[bn + t], rQ[wcc][nff][0][c] + rQ[wcc][nff][1][c]);
  }
}

// ---------------------------------------------------------------------------
// prep2: W2p[i][j] = bf16(W2[i][j] * a1[j]), a1 inline from atomic stats.
// Output 512 x 448 (zeros beyond row<400 / col<400). Grid 224 x 256.
// ---------------------------------------------------------------------------
__global__ __launch_bounds__(256) void prep2(
    const float* __restrict__ aS1, const float* __restrict__ aQ1,
    const float* __restrict__ g1, const float* __restrict__ W2,
    u16* __restrict__ W2p) {
  const int c = blockIdx.x * 256 + threadIdx.x;  // 512*112 chunks
  const int row = c / 112;
  const int jc = (c - row * 112) * 4;
  ushort4 o = {0, 0, 0, 0};
  if (row < 400 && jc < 400) {
    const float4 S = *(const float4*)&aS1[jc];
    const float4 Q = *(const float4*)&aQ1[jc];
    const float4 G = *(const float4*)&g1[jc];
    const float4 w = *(const float4*)&W2[(size_t)row * 400 + jc];
    const float inv = 1.f / 16384.f;
    float mu, var, a;
    mu = S.x * inv; var = Q.x * inv - mu * mu;
    a = G.x * rsqrtf(var + BN_EPS); o.x = f2bf(w.x * a);
    mu = S.y * inv; var = Q.y * inv - mu * mu;
    a = G.y * rsqrtf(var + BN_EPS); o.y = f2bf(w.y * a);
    mu = S.z * inv; var = Q.z * inv - mu * mu;
    a = G.z * rsqrtf(var + BN_EPS); o.z = f2bf(w.z * a);
    mu = S.w * inv; var = Q.w * inv - mu * mu;
    a = G.w * rsqrtf(var + BN_EPS); o.w = f2bf(w.w * a);
  }
  *(ushort4*)&W2p[(size_t)row * 448 + jc] = o;
}

// ---------------------------------------------------------------------------
// final: BN2 affine inline per lane (8 cols) + row dot.
// ---------------------------------------------------------------------------
__device__ __forceinline__ void bn_affine4(const float* aS, const float* aQ,
                                           const float* g, const float* be,
                                           int j, float4& aa, float4& cc) {
  const float4 S = *(const float4*)&aS[j];
  const float4 Q = *(const float4*)&aQ[j];
  const float4 G = *(const float4*)&g[j];
  const float4 E = *(const float4*)&be[j];
  const float inv = 1.f / 16384.f;
  float mu, var;
  mu = S.x * inv; var = Q.x * inv - mu * mu;
  aa.x = G.x * rsqrtf(var + BN_EPS); cc.x = E.x - mu * aa.x;
  mu = S.y * inv; var = Q.y * inv - mu * mu;
  aa.y = G.y * rsqrtf(var + BN_EPS); cc.y = E.y - mu * aa.y;
  mu = S.z * inv; var = Q.z * inv - mu * mu;
  aa.z = G.z * rsqrtf(var + BN_EPS); cc.z = E.z - mu * aa.z;
  mu = S.w * inv; var = Q.w * inv - mu * mu;
  aa.w = G.w * rsqrtf(var + BN_EPS); cc.w = E.w - mu * aa.w;
}

__global__ __launch_bounds__(256) void final_kernel(
    const u16* __restrict__ Y2, const float* __restrict__ aS2,
    const float* __restrict__ aQ2, const float* __restrict__ g2,
    const float* __restrict__ be2, const float* __restrict__ partial,
    float* __restrict__ out) {
  const int t = threadIdx.x;
  const int lane = t & 63;
  const int wid = t >> 6;
  const int j0 = lane * 8;
  float ar[8], cr[8];
  if (j0 < 400) {
    float4 aa0, cc0, aa1, cc1;
    bn_affine4(aS2, aQ2, g2, be2, j0, aa0, cc0);
    bn_affine4(aS2, aQ2, g2, be2, j0 + 4, aa1, cc1);
    ar[0] = aa0.x; ar[1] = aa0.y; ar[2] = aa0.z; ar[3] = aa0.w;
    ar[4] = aa1.x; ar[5] = aa1.y; ar[6] = aa1.z; ar[7] = aa1.w;
    cr[0] = cc0.x; cr[1] = cc0.y; cr[2] = cc0.z; cr[3] = cc0.w;
    cr[4] = cc1.x; cr[5] = cc1.y; cr[6] = cc1.z; cr[7] = cc1.w;
  } else {
#pragma unroll
    for (int k = 0; k < 8; ++k) { ar[k] = 0.f; cr[k] = 0.f; }
  }
#pragma unroll
  for (int r = 0; r < 4; ++r) {
    const int n = blockIdx.x * 16 + wid * 4 + r;
    float acc = 0.f;
    if (j0 < 400) {
      const bf16x8 y = *(const bf16x8*)&Y2[(size_t)n * 400 + j0];
#pragma unroll
      for (int k = 0; k < 8; ++k)
        acc += fmaf(ar[k], bf2f((u16)y[k]), cr[k]);
    }
    acc = wave_reduce_sum(acc);
    if (lane == 0) out[n] = partial[n] + acc;
  }
}

extern "C" void kernel_launch(void* const* d_in, const int* in_sizes, int n_in,
                              void* d_out, int out_size, void* d_ws,
                              size_t ws_size, hipStream_t stream) {
  const float* Xi_dense = (const float*)d_in[0];
  const float* Xv = (const float*)d_in[1];
  const float* Wd = (const float*)d_in[2];
  const float* bd = (const float*)d_in[3];
  const float* tables = (const float*)d_in[4];
  const float* W1 = (const float*)d_in[5];
  const float* g1 = (const float*)d_in[7];
  const float* W2 = (const float*)d_in[9];
  const float* g2 = (const float*)d_in[11];
  const float* be2 = (const float*)d_in[12];
  const float* bias_vec = (const float*)d_in[13];
  const int* Xi_cat = (const int*)d_in[14];

  constexpr int N = 16384;
  constexpr int DIN = 576;
  constexpr int H = 400;
  constexpr int KP = 448;   // H padded to K-mult-of-64 for gemm2
  constexpr int WPAD = 512; // weight rows padded for unpredicated staging

  u16* fm_first = (u16*)d_ws;                        // N*576
  u16* Y1h = fm_first + (size_t)N * DIN;             // N*448
  u16* Y2h = Y1h + (size_t)N * KP;                   // N*400
  u16* W1h = Y2h + (size_t)N * H;                    // 512*576
  u16* W2p = W1h + (size_t)WPAD * DIN;               // 512*448
  float* fptr = (float*)(W2p + (size_t)WPAD * KP);
  float* partial = fptr;                             // N
  float* aS1 = partial + N;                          // 512 (stats; 2048
  float* aQ1 = aS1 + WPAD;                           //  floats zeroed by
  float* aS2 = aQ1 + WPAD;                           //  embed block 512)
  float* aQ2 = aS2 + WPAD;

  embed_prep<<<512 + 72, 256, 0, stream>>>(Xi_dense, Xv, Wd, bd, tables,
                                           Xi_cat, bias_vec, W1, fm_first,
                                           partial, W1h, aS1);

  gemm_bf16<<<512, 256, 0, stream>>>(fm_first, DIN, W1h, DIN,
                                     Y1h, KP, KP, aS1, aQ1, DIN);

  prep2<<<224, 256, 0, stream>>>(aS1, aQ1, g1, W2, W2p);

  gemm_bf16<<<512, 256, 0, stream>>>(Y1h, KP, W2p, KP,
                                     Y2h, H, H, aS2, aQ2, KP);

  final_kernel<<<N / 16, 256, 0, stream>>>(Y2h, aS2, aQ2, g2, be2, partial,
                                           (float*)d_out);
}